// Round 13
// baseline (989.668 us; speedup 1.0000x reference)
//
#include <hip/hip_runtime.h>
#include <math.h>

#define T_TOKENS 2048
#define H_DIM 2048
#define E_NUM 64
#define I_DIM 768
#define TOPK 8
#define CAP 1024
#define TK (T_TOKENS * TOPK)
#define RCHG 256           // rows per super-pass (4 x 64)
#define NTG (H_DIM / 32)   // 64 K-steps (gu), even
#define NTD (I_DIM / 32)   // 24 K-steps (down), even

typedef __attribute__((ext_vector_type(8))) short s8v;
typedef __attribute__((ext_vector_type(4))) float f32x4;

__device__ inline unsigned short f2bf(float f) {
    union { float f; unsigned int u; } v; v.f = f;
    return (unsigned short)((v.u + 0x7FFFu + ((v.u >> 16) & 1u)) >> 16);
}
__device__ inline unsigned int pack2(float lo, float hi) {
    unsigned int r;
    asm("v_cvt_pk_bf16_f32 %0, %1, %2" : "=v"(r) : "v"(lo), "v"(hi));
    return r;
}

// raw barrier (no vmcnt(0) drain) + LDS-visibility fence
#define SBAR() __builtin_amdgcn_s_barrier()
#define LGKM0()                                            \
    do {                                                   \
        asm volatile("s_waitcnt lgkmcnt(0)" ::: "memory"); \
        __builtin_amdgcn_sched_barrier(0);                 \
    } while (0)

// ---------------- init counts ----------------
__global__ void init_cnt_kernel(int* __restrict__ cnt) {
    if (threadIdx.x < E_NUM) cnt[threadIdx.x] = 0;
}

// ---------------- zero output (atomic fallback path only) ----------------
__global__ __launch_bounds__(256) void zero_out_kernel(float* __restrict__ out, int n4) {
    int i = blockIdx.x * 256 + threadIdx.x;
    if (i < n4) reinterpret_cast<float4*>(out)[i] = make_float4(0.f, 0.f, 0.f, 0.f);
}

// ---------------- router: 4 tokens/block, fp32 logits (proven) + fused x->bf16 ----------------
__global__ __launch_bounds__(256) void router_kernel(const float* __restrict__ x,
                                                     const float* __restrict__ wr,
                                                     int* __restrict__ topi,
                                                     float* __restrict__ topw,
                                                     unsigned short* __restrict__ xbf) {
    __shared__ float xs[4][H_DIM];
    __shared__ float lg[4][E_NUM];
    int t0 = blockIdx.x * 4;
    int tid = threadIdx.x;
    #pragma unroll
    for (int r = 0; r < 4; ++r) {
        const float* xrow = x + (size_t)(t0 + r) * H_DIM + tid * 8;
        float4 a = *reinterpret_cast<const float4*>(xrow);
        float4 b = *reinterpret_cast<const float4*>(xrow + 4);
        *reinterpret_cast<float4*>(&xs[r][tid * 8])     = a;
        *reinterpret_cast<float4*>(&xs[r][tid * 8 + 4]) = b;
        int4 o;
        o.x = (int)pack2(a.x, a.y);
        o.y = (int)pack2(a.z, a.w);
        o.z = (int)pack2(b.x, b.y);
        o.w = (int)pack2(b.z, b.w);
        *reinterpret_cast<int4*>(xbf + (size_t)(t0 + r) * H_DIM + tid * 8) = o;
    }
    __syncthreads();
    int w = tid >> 6, lane = tid & 63;
    for (int eo = 0; eo < 16; ++eo) {
        int e = w * 16 + eo;
        const float* wrow = wr + (size_t)e * H_DIM;
        float a0 = 0.f, a1 = 0.f, a2 = 0.f, a3 = 0.f;
        for (int h = lane; h < H_DIM; h += 64) {
            float wv = wrow[h];
            a0 += wv * xs[0][h]; a1 += wv * xs[1][h];
            a2 += wv * xs[2][h]; a3 += wv * xs[3][h];
        }
        #pragma unroll
        for (int off = 32; off; off >>= 1) {
            a0 += __shfl_xor(a0, off); a1 += __shfl_xor(a1, off);
            a2 += __shfl_xor(a2, off); a3 += __shfl_xor(a3, off);
        }
        if (lane == 0) { lg[0][e] = a0; lg[1][e] = a1; lg[2][e] = a2; lg[3][e] = a3; }
    }
    __syncthreads();
    if (tid < 32) {
        int r = tid >> 3, rank = tid & 7;
        const float* lgr = lg[r];
        float pv = 3.4e38f; int pi = -1;
        float m = 0.f, s = 0.f, myv = 0.f; int myi = 0;
        for (int q = 0; q < TOPK; ++q) {
            float best = -3.4e38f; int bi = -1;
            for (int e2 = 0; e2 < E_NUM; ++e2) {
                float v = lgr[e2];
                bool excl = (v > pv) || (v == pv && e2 <= pi);
                if (!excl && v > best) { best = v; bi = e2; }
            }
            if (q == 0) m = best;
            s += expf(best - m);
            if (q == rank) { myv = best; myi = bi; }
            pv = best; pi = bi;
        }
        topw[(t0 + r) * TOPK + rank] = expf(myv - m) / s;
        topi[(t0 + r) * TOPK + rank] = myi;
    }
}

// ---------------- dispatch / offsets ----------------
__global__ __launch_bounds__(256) void dispatch_kernel(const int* __restrict__ topi,
                                                       int* __restrict__ cnt,
                                                       int* __restrict__ slot,
                                                       int* __restrict__ epos) {
    int i = blockIdx.x * 256 + threadIdx.x;
    int e = topi[i];
    int pos = atomicAdd(cnt + e, 1);
    epos[i] = pos;
    if (pos < CAP) slot[e * CAP + pos] = i;
}

__global__ void offs_kernel(const int* __restrict__ cnt, int* __restrict__ offs) {
    if (threadIdx.x == 0) {
        int run = 0;
        for (int e = 0; e < E_NUM; ++e) {
            offs[e] = run;
            int c = cnt[e]; if (c > CAP) c = CAP;
            run += c;
        }
    }
}

// ---------------- GEMM A: (64-I-col strip, expert), counted-vmcnt 2-deep pipeline ----------
__global__ __launch_bounds__(256, 2) void gemm_gu_kernel(const unsigned short* __restrict__ xbf,
                                                         const float* __restrict__ gup,
                                                         const int* __restrict__ slot,
                                                         const int* __restrict__ cnt,
                                                         const int* __restrict__ offs,
                                                         unsigned short* __restrict__ hws) {
    int e = blockIdx.y;
    int rows = min(cnt[e], CAP);
    int c0 = blockIdx.x * 64;
    int off_e = offs[e];

    __shared__ unsigned short As[2][RCHG][40];
    __shared__ unsigned short Bt[2][128][40];

    int tid = threadIdx.x;
    int w = tid >> 6, lane = tid & 63, grp = lane >> 4, l15 = lane & 15;

    // B map (r8, conflict-minimal b128 writes): thread -> (colB, k-half)
    int colB = tid & 127, khalf = tid >> 7;
    int gcol = (colB < 64) ? (c0 + colB) : (I_DIM + c0 + (colB - 64));
    const float* bbase = gup + ((size_t)e * H_DIM + khalf * 16) * (2 * I_DIM) + gcol;

    int arow = tid >> 2, aq = tid & 3;

    for (int s0 = 0; s0 < rows; s0 += RCHG) {
        int nch = min(4, (rows - s0 + 63) >> 6);
        const unsigned short* ab[4];
        #pragma unroll
        for (int p = 0; p < 4; ++p) {
            int rg = s0 + p * 64 + arow;
            int ent = slot[e * CAP + min(rg, rows - 1)];
            ab[p] = xbf + (size_t)(ent >> 3) * H_DIM + aq * 8;
        }

        f32x4 acc[4][8];
        #pragma unroll
        for (int p = 0; p < 4; ++p)
            #pragma unroll
            for (int f = 0; f < 8; ++f) acc[p][f] = (f32x4){0.f, 0.f, 0.f, 0.f};

        float pb0[16], pb1[16];
        int4 pa[4];

#define LOADB(S, KK)                                                             \
        {                                                                        \
            _Pragma("unroll")                                                    \
            for (int j = 0; j < 16; ++j)                                         \
                S[j] = bbase[(size_t)((KK) + j) * (2 * I_DIM)];                  \
        }
#define PACKB(B, S)                                                              \
        {                                                                        \
            unsigned int bw[8];                                                  \
            _Pragma("unroll")                                                    \
            for (int j = 0; j < 8; ++j) bw[j] = pack2(S[2 * j], S[2 * j + 1]);   \
            *reinterpret_cast<int4*>(&Bt[B][colB][khalf * 16])     = make_int4(bw[0], bw[1], bw[2], bw[3]); \
            *reinterpret_cast<int4*>(&Bt[B][colB][khalf * 16 + 8]) = make_int4(bw[4], bw[5], bw[6], bw[7]); \
        }
#define LOADA(KK)                                                                \
        {                                                                        \
            _Pragma("unroll")                                                    \
            for (int p = 0; p < 4; ++p)                                          \
                if (p < nch) pa[p] = *reinterpret_cast<const int4*>(ab[p] + (KK)); \
        }
#define PACKA(B)                                                                 \
        {                                                                        \
            _Pragma("unroll")                                                    \
            for (int p = 0; p < 4; ++p)                                          \
                if (p < nch) *reinterpret_cast<int4*>(&As[B][p * 64 + arow][aq * 8]) = pa[p]; \
        }
#define COMPUTE(B)                                                               \
        {                                                                        \
            s8v bf[8];                                                           \
            _Pragma("unroll")                                                    \
            for (int f = 0; f < 8; ++f)                                          \
                bf[f] = *reinterpret_cast<const s8v*>(&Bt[B][f * 16 + l15][grp * 8]); \
            _Pragma("unroll")                                                    \
            for (int p = 0; p < 4; ++p) {                                        \
                if (p < nch) {                                                   \
                    s8v a = *reinterpret_cast<const s8v*>(&As[B][p * 64 + w * 16 + l15][grp * 8]); \
                    _Pragma("unroll")                                            \
                    for (int f = 0; f < 8; ++f)                                  \
                        acc[p][f] = __builtin_amdgcn_mfma_f32_16x16x32_bf16(a, bf[f], acc[p][f], 0, 0, 0); \
                }                                                                \
            }                                                                    \
        }

        // prologue: tile0 B+A, tile1 B in flight
        LOADB(pb0, 0);
        LOADA(0);
        LOADB(pb1, 32);

        for (int tt = 0; tt < NTG; tt += 2) {
            // ---- phase tt (buf 0, set pb0) ----
            PACKB(0, pb0);           // compiler inserts counted vmcnt for pb0/pa here
            PACKA(0);
            LGKM0();
            SBAR();                  // writes visible; NO vmcnt drain
            COMPUTE(0);
            if (tt + 1 < NTG) LOADA((tt + 1) * 32);
            if (tt + 2 < NTG) LOADB(pb0, (tt + 2) * 32);
            SBAR();                  // read-protect
            // ---- phase tt+1 (buf 1, set pb1) ----
            PACKB(1, pb1);
            PACKA(1);
            LGKM0();
            SBAR();
            COMPUTE(1);
            if (tt + 2 < NTG) LOADA((tt + 2) * 32);
            if (tt + 3 < NTG) LOADB(pb1, (tt + 3) * 32);
            SBAR();
        }
#undef LOADB
#undef PACKB
#undef LOADA
#undef PACKA
#undef COMPUTE

        #pragma unroll
        for (int p = 0; p < 4; ++p) {
            if (p < nch) {
                #pragma unroll
                for (int f = 0; f < 4; ++f) {
                    #pragma unroll
                    for (int r = 0; r < 4; ++r) {
                        int rg = s0 + p * 64 + w * 16 + grp * 4 + r;
                        if (rg < rows) {
                            float g = acc[p][f][r];
                            float u = acc[p][f + 4][r];
                            float hv = (g / (1.f + expf(-g))) * u;
                            hws[(size_t)(off_e + rg) * I_DIM + (c0 + f * 16 + l15)] = f2bf(hv);
                        }
                    }
                }
            }
        }
        __syncthreads();   // super-pass boundary: full drain is fine here (rare)
    }
}

// ---------------- GEMM B: (128-H-col strip, expert), counted-vmcnt 2-deep pipeline --------
__global__ __launch_bounds__(256, 2) void gemm_down_kernel(const unsigned short* __restrict__ hws,
                                                           const float* __restrict__ dwn,
                                                           const int* __restrict__ slot,
                                                           const int* __restrict__ cnt,
                                                           const int* __restrict__ offs,
                                                           const float* __restrict__ topw,
                                                           float* __restrict__ out,
                                                           unsigned short* __restrict__ ye,
                                                           int use_ye) {
    int e = blockIdx.y;
    int rows = min(cnt[e], CAP);
    int c0 = blockIdx.x * 128;
    int off_e = offs[e];

    __shared__ unsigned short As[2][RCHG][40];
    __shared__ unsigned short Bt[2][128][40];

    int tid = threadIdx.x;
    int w = tid >> 6, lane = tid & 63, grp = lane >> 4, l15 = lane & 15;

    int colB = tid & 127, khalf = tid >> 7;
    const float* bbase = dwn + ((size_t)e * I_DIM + khalf * 16) * H_DIM + c0 + colB;

    int arow = tid >> 2, aq = tid & 3;

    for (int s0 = 0; s0 < rows; s0 += RCHG) {
        int nch = min(4, (rows - s0 + 63) >> 6);
        const unsigned short* ab[4];
        #pragma unroll
        for (int p = 0; p < 4; ++p) {
            int rg = s0 + p * 64 + arow;
            ab[p] = hws + (size_t)(off_e + min(rg, rows - 1)) * I_DIM + aq * 8;
        }

        f32x4 acc[4][8];
        #pragma unroll
        for (int p = 0; p < 4; ++p)
            #pragma unroll
            for (int f = 0; f < 8; ++f) acc[p][f] = (f32x4){0.f, 0.f, 0.f, 0.f};

        float pb0[16], pb1[16];
        int4 pa[4];

#define LOADB(S, KK)                                                             \
        {                                                                        \
            _Pragma("unroll")                                                    \
            for (int j = 0; j < 16; ++j)                                         \
                S[j] = bbase[(size_t)((KK) + j) * H_DIM];                        \
        }
#define PACKB(B, S)                                                              \
        {                                                                        \
            unsigned int bw[8];                                                  \
            _Pragma("unroll")                                                    \
            for (int j = 0; j < 8; ++j) bw[j] = pack2(S[2 * j], S[2 * j + 1]);   \
            *reinterpret_cast<int4*>(&Bt[B][colB][khalf * 16])     = make_int4(bw[0], bw[1], bw[2], bw[3]); \
            *reinterpret_cast<int4*>(&Bt[B][colB][khalf * 16 + 8]) = make_int4(bw[4], bw[5], bw[6], bw[7]); \
        }
#define LOADA(KK)                                                                \
        {                                                                        \
            _Pragma("unroll")                                                    \
            for (int p = 0; p < 4; ++p)                                          \
                if (p < nch) pa[p] = *reinterpret_cast<const int4*>(ab[p] + (KK)); \
        }
#define PACKA(B)                                                                 \
        {                                                                        \
            _Pragma("unroll")                                                    \
            for (int p = 0; p < 4; ++p)                                          \
                if (p < nch) *reinterpret_cast<int4*>(&As[B][p * 64 + arow][aq * 8]) = pa[p]; \
        }
#define COMPUTE(B)                                                               \
        {                                                                        \
            s8v bf[8];                                                           \
            _Pragma("unroll")                                                    \
            for (int f = 0; f < 8; ++f)                                          \
                bf[f] = *reinterpret_cast<const s8v*>(&Bt[B][f * 16 + l15][grp * 8]); \
            _Pragma("unroll")                                                    \
            for (int p = 0; p < 4; ++p) {                                        \
                if (p < nch) {                                                   \
                    s8v a = *reinterpret_cast<const s8v*>(&As[B][p * 64 + w * 16 + l15][grp * 8]); \
                    _Pragma("unroll")                                            \
                    for (int f = 0; f < 8; ++f)                                  \
                        acc[p][f] = __builtin_amdgcn_mfma_f32_16x16x32_bf16(a, bf[f], acc[p][f], 0, 0, 0); \
                }                                                                \
            }                                                                    \
        }

        LOADB(pb0, 0);
        LOADA(0);
        LOADB(pb1, 32);

        for (int tt = 0; tt < NTD; tt += 2) {
            PACKB(0, pb0);
            PACKA(0);
            LGKM0();
            SBAR();
            COMPUTE(0);
            if (tt + 1 < NTD) LOADA((tt + 1) * 32);
            if (tt + 2 < NTD) LOADB(pb0, (tt + 2) * 32);
            SBAR();
            PACKB(1, pb1);
            PACKA(1);
            LGKM0();
            SBAR();
            COMPUTE(1);
            if (tt + 2 < NTD) LOADA((tt + 2) * 32);
            if (tt + 3 < NTD) LOADB(pb1, (tt + 3) * 32);
            SBAR();
        }
#undef LOADB
#undef PACKB
#undef LOADA
#undef PACKA
#undef COMPUTE

        if (use_ye) {
            #pragma unroll
            for (int p = 0; p < 4; ++p) {
                if (p < nch) {
                    #pragma unroll
                    for (int r = 0; r < 4; ++r) {
                        int rg = s0 + p * 64 + w * 16 + grp * 4 + r;
                        if (rg < rows) {
                            unsigned short* yrow = ye + (size_t)(off_e + rg) * H_DIM + c0 + l15;
                            #pragma unroll
                            for (int f = 0; f < 8; ++f)
                                yrow[f * 16] = f2bf(acc[p][f][r]);
                        }
                    }
                }
            }
        } else {
            #pragma unroll
            for (int p = 0; p < 4; ++p) {
                if (p < nch) {
                    #pragma unroll
                    for (int r = 0; r < 4; ++r) {
                        int rg = s0 + p * 64 + w * 16 + grp * 4 + r;
                        if (rg < rows) {
                            int ent2 = slot[e * CAP + rg];
                            float wgt = topw[ent2];
                            float* obase = out + (size_t)(ent2 >> 3) * H_DIM + c0 + l15;
                            #pragma unroll
                            for (int f = 0; f < 8; ++f)
                                atomicAdd(obase + f * 16, wgt * acc[p][f][r]);
                        }
                    }
                }
            }
        }
        __syncthreads();
    }
}

// ---------------- combine (ye path) ----------------
__global__ __launch_bounds__(256) void combine_kernel(const unsigned short* __restrict__ ye,
                                                      const int* __restrict__ topi,
                                                      const float* __restrict__ topw,
                                                      const int* __restrict__ epos,
                                                      const int* __restrict__ offs,
                                                      float* __restrict__ out) {
    int t = blockIdx.x;
    int tid = threadIdx.x;
    int base = t * TOPK;
    float acc[8];
    #pragma unroll
    for (int j = 0; j < 8; ++j) acc[j] = 0.f;
    #pragma unroll
    for (int k = 0; k < TOPK; ++k) {
        int e = topi[base + k];
        int p = epos[base + k];
        if (p < CAP) {
            int row = offs[e] + p;
            float wk = topw[base + k];
            int4 v = *reinterpret_cast<const int4*>(ye + (size_t)row * H_DIM + tid * 8);
            const unsigned short* vp = reinterpret_cast<const unsigned short*>(&v);
            #pragma unroll
            for (int j = 0; j < 8; ++j)
                acc[j] += wk * __uint_as_float(((unsigned int)vp[j]) << 16);
        }
    }
    float* orow = out + (size_t)t * H_DIM + tid * 8;
    *reinterpret_cast<float4*>(orow)     = make_float4(acc[0], acc[1], acc[2], acc[3]);
    *reinterpret_cast<float4*>(orow + 4) = make_float4(acc[4], acc[5], acc[6], acc[7]);
}

extern "C" void kernel_launch(void* const* d_in, const int* in_sizes, int n_in,
                              void* d_out, int out_size, void* d_ws, size_t ws_size,
                              hipStream_t stream) {
    const float* x   = (const float*)d_in[0];
    const float* wr  = (const float*)d_in[1];
    const float* gup = (const float*)d_in[2];
    const float* dwn = (const float*)d_in[3];
    float* out = (float*)d_out;
    char* ws = (char*)d_ws;

    int*            topi = (int*)(ws + 0);         //  64 KB
    float*          topw = (float*)(ws + 65536);   //  64 KB
    int*            cnt  = (int*)(ws + 131072);    // 256 B
    int*            offs = (int*)(ws + 131328);    // 256 B
    int*            epos = (int*)(ws + 131584);    //  64 KB
    int*            slot = (int*)(ws + 197120);    // 256 KB
    unsigned short* hws  = (unsigned short*)(ws + 459264);   // 24 MB
    unsigned short* xbf  = (unsigned short*)(ws + 33554432); //  8 MB
    unsigned short* ye   = (unsigned short*)(ws + 50331648); // 64 MB (ye path only)

    int use_ye = (ws_size >= (size_t)125829120) ? 1 : 0;

    init_cnt_kernel<<<1, 64, 0, stream>>>(cnt);
    if (!use_ye) {
        int n4 = out_size / 4;
        zero_out_kernel<<<(n4 + 255) / 256, 256, 0, stream>>>(out, n4);
    }
    router_kernel<<<T_TOKENS / 4, 256, 0, stream>>>(x, wr, topi, topw, xbf);
    dispatch_kernel<<<TK / 256, 256, 0, stream>>>(topi, cnt, slot, epos);
    offs_kernel<<<1, 64, 0, stream>>>(cnt, offs);
    gemm_gu_kernel<<<dim3(12, 64), 256, 0, stream>>>(xbf, gup, slot, cnt, offs, hws);
    gemm_down_kernel<<<dim3(16, 64), 256, 0, stream>>>(hws, dwn, slot, cnt, offs, topw, out, ye, use_ye);
    if (use_ye)
        combine_kernel<<<T_TOKENS, 256, 0, stream>>>(ye, topi, topw, epos, offs, out);
}

// Round 14
// 858.251 us; speedup vs baseline: 1.1531x; 1.1531x over previous
//
#include <hip/hip_runtime.h>
#include <math.h>

#define T_TOKENS 2048
#define H_DIM 2048
#define E_NUM 64
#define I_DIM 768
#define TOPK 8
#define CAP 1024
#define TK (T_TOKENS * TOPK)
#define RCHG 256           // rows per super-pass (4 x 64)
#define NTG (H_DIM / 32)   // 64 K-steps (gu)
#define NTD (I_DIM / 32)   // 24 K-steps (down)

typedef __attribute__((ext_vector_type(8))) short s8v;
typedef __attribute__((ext_vector_type(4))) float f32x4;

__device__ inline unsigned short f2bf(float f) {
    union { float f; unsigned int u; } v; v.f = f;
    return (unsigned short)((v.u + 0x7FFFu + ((v.u >> 16) & 1u)) >> 16);
}
// packed RNE f32->bf16x2 (single VALU instruction)
__device__ inline unsigned int pack2(float lo, float hi) {
    unsigned int r;
    asm("v_cvt_pk_bf16_f32 %0, %1, %2" : "=v"(r) : "v"(lo), "v"(hi));
    return r;
}

// ---------------- init counts ----------------
__global__ void init_cnt_kernel(int* __restrict__ cnt) {
    if (threadIdx.x < E_NUM) cnt[threadIdx.x] = 0;
}

// ---------------- zero output (atomic fallback path only) ----------------
__global__ __launch_bounds__(256) void zero_out_kernel(float* __restrict__ out, int n4) {
    int i = blockIdx.x * 256 + threadIdx.x;
    if (i < n4) reinterpret_cast<float4*>(out)[i] = make_float4(0.f, 0.f, 0.f, 0.f);
}

// ---------------- router: 4 tokens/block (r7-proven) ----------------
__global__ __launch_bounds__(256) void router_kernel(const float* __restrict__ x,
                                                     const float* __restrict__ wr,
                                                     int* __restrict__ topi,
                                                     float* __restrict__ topw) {
    __shared__ float xs[4][H_DIM];
    __shared__ float lg[4][E_NUM];
    int t0 = blockIdx.x * 4;
    int tid = threadIdx.x;
    #pragma unroll
    for (int r = 0; r < 4; ++r) {
        const float* xrow = x + (size_t)(t0 + r) * H_DIM + tid * 8;
        *reinterpret_cast<float4*>(&xs[r][tid * 8])     = *reinterpret_cast<const float4*>(xrow);
        *reinterpret_cast<float4*>(&xs[r][tid * 8 + 4]) = *reinterpret_cast<const float4*>(xrow + 4);
    }
    __syncthreads();
    int w = tid >> 6, lane = tid & 63;
    for (int eo = 0; eo < 16; ++eo) {
        int e = w * 16 + eo;
        const float* wrow = wr + (size_t)e * H_DIM;
        float a0 = 0.f, a1 = 0.f, a2 = 0.f, a3 = 0.f;
        for (int h = lane; h < H_DIM; h += 64) {
            float wv = wrow[h];
            a0 += wv * xs[0][h]; a1 += wv * xs[1][h];
            a2 += wv * xs[2][h]; a3 += wv * xs[3][h];
        }
        #pragma unroll
        for (int off = 32; off; off >>= 1) {
            a0 += __shfl_xor(a0, off); a1 += __shfl_xor(a1, off);
            a2 += __shfl_xor(a2, off); a3 += __shfl_xor(a3, off);
        }
        if (lane == 0) { lg[0][e] = a0; lg[1][e] = a1; lg[2][e] = a2; lg[3][e] = a3; }
    }
    __syncthreads();
    if (tid < 32) {
        int r = tid >> 3, rank = tid & 7;
        const float* lgr = lg[r];
        float pv = 3.4e38f; int pi = -1;
        float m = 0.f, s = 0.f, myv = 0.f; int myi = 0;
        for (int q = 0; q < TOPK; ++q) {
            float best = -3.4e38f; int bi = -1;
            for (int e2 = 0; e2 < E_NUM; ++e2) {
                float v = lgr[e2];
                bool excl = (v > pv) || (v == pv && e2 <= pi);
                if (!excl && v > best) { best = v; bi = e2; }
            }
            if (q == 0) m = best;
            s += expf(best - m);
            if (q == rank) { myv = best; myi = bi; }
            pv = best; pi = bi;
        }
        topw[(t0 + r) * TOPK + rank] = expf(myv - m) / s;
        topi[(t0 + r) * TOPK + rank] = myi;
    }
}

// ---------------- dispatch / offsets ----------------
__global__ __launch_bounds__(256) void dispatch_kernel(const int* __restrict__ topi,
                                                       int* __restrict__ cnt,
                                                       int* __restrict__ slot,
                                                       int* __restrict__ epos) {
    int i = blockIdx.x * 256 + threadIdx.x;
    int e = topi[i];
    int pos = atomicAdd(cnt + e, 1);
    epos[i] = pos;
    if (pos < CAP) slot[e * CAP + pos] = i;
}

__global__ void offs_kernel(const int* __restrict__ cnt, int* __restrict__ offs) {
    if (threadIdx.x == 0) {
        int run = 0;
        for (int e = 0; e < E_NUM; ++e) {
            offs[e] = run;
            int c = cnt[e]; if (c > CAP) c = CAP;
            run += c;
        }
    }
}

// ---------------- GEMM A (r7-861 body + expert->XCD swizzle) ----------
// flat grid 12*64; bid = g*(12*8) + s*8 + (e&7)  =>  same expert -> same XCD
__global__ __launch_bounds__(256, 2) void gemm_gu_kernel(const float* __restrict__ x,
                                                         const float* __restrict__ gup,
                                                         const int* __restrict__ slot,
                                                         const int* __restrict__ cnt,
                                                         const int* __restrict__ offs,
                                                         unsigned short* __restrict__ hws) {
    int bid = blockIdx.x;
    int xl = bid & 7;
    int tq = bid >> 3;
    int s  = tq % 12;
    int e  = (tq / 12) * 8 + xl;
    int rows = min(cnt[e], CAP);
    int c0 = s * 64;
    int off_e = offs[e];

    __shared__ unsigned short As[2][RCHG][40];   // [buf][row][k32+pad]
    __shared__ unsigned short Bt[2][128][40];    // [buf][colL][k32+pad]; L<64 gate, L>=64 up

    int tid = threadIdx.x;
    int w = tid >> 6, lane = tid & 63, grp = lane >> 4, l15 = lane & 15;

    // B map: thread -> (colL, k-half of 16)
    int colB = tid & 127, khalf = tid >> 7;
    int gcol = (colB < 64) ? (c0 + colB) : (I_DIM + c0 + (colB - 64));
    const float* bbase = gup + ((size_t)e * H_DIM + khalf * 16) * (2 * I_DIM) + gcol;

    // A map: thread -> (row-in-chunk, 8-float quarter), per chunk
    int arow = tid >> 2, aq = tid & 3;

    for (int s0 = 0; s0 < rows; s0 += RCHG) {
        int nch = min(4, (rows - s0 + 63) >> 6);
        const float* ab[4];
        #pragma unroll
        for (int p = 0; p < 4; ++p) {
            int rg = s0 + p * 64 + arow;
            int ent = slot[e * CAP + min(rg, rows - 1)];
            ab[p] = x + (size_t)(ent >> 3) * H_DIM + aq * 8;
        }

        f32x4 acc[4][8];
        #pragma unroll
        for (int p = 0; p < 4; ++p)
            #pragma unroll
            for (int f = 0; f < 8; ++f) acc[p][f] = (f32x4){0.f, 0.f, 0.f, 0.f};

        float pb[16];
        float4 pa0[4], pa1[4];

        // prologue: load + pack + write tile 0 into buf 0
        #pragma unroll
        for (int j = 0; j < 16; ++j) pb[j] = bbase[(size_t)j * (2 * I_DIM)];
        #pragma unroll
        for (int p = 0; p < 4; ++p) {
            if (p < nch) {
                pa0[p] = *reinterpret_cast<const float4*>(ab[p]);
                pa1[p] = *reinterpret_cast<const float4*>(ab[p] + 4);
            }
        }
        {
            unsigned int bw[8];
            #pragma unroll
            for (int j = 0; j < 8; ++j) bw[j] = pack2(pb[2 * j], pb[2 * j + 1]);
            *reinterpret_cast<int4*>(&Bt[0][colB][khalf * 16])     = make_int4(bw[0], bw[1], bw[2], bw[3]);
            *reinterpret_cast<int4*>(&Bt[0][colB][khalf * 16 + 8]) = make_int4(bw[4], bw[5], bw[6], bw[7]);
            #pragma unroll
            for (int p = 0; p < 4; ++p) {
                if (p < nch) {
                    int4 ao;
                    ao.x = (int)pack2(pa0[p].x, pa0[p].y);
                    ao.y = (int)pack2(pa0[p].z, pa0[p].w);
                    ao.z = (int)pack2(pa1[p].x, pa1[p].y);
                    ao.w = (int)pack2(pa1[p].z, pa1[p].w);
                    *reinterpret_cast<int4*>(&As[0][p * 64 + arow][aq * 8]) = ao;
                }
            }
        }
        __syncthreads();

        for (int t = 0; t < NTG; ++t) {
            int cur = t & 1;
            int kn = (t + 1) * 32;
            if (t + 1 < NTG) {
                // issue next-tile global loads (consumed after compute)
                #pragma unroll
                for (int j = 0; j < 16; ++j) pb[j] = bbase[(size_t)(kn + j) * (2 * I_DIM)];
                #pragma unroll
                for (int p = 0; p < 4; ++p) {
                    if (p < nch) {
                        pa0[p] = *reinterpret_cast<const float4*>(ab[p] + kn);
                        pa1[p] = *reinterpret_cast<const float4*>(ab[p] + kn + 4);
                    }
                }
            }
            // compute tile t from buf[cur]
            {
                s8v bf[8];
                #pragma unroll
                for (int f = 0; f < 8; ++f)
                    bf[f] = *reinterpret_cast<const s8v*>(&Bt[cur][f * 16 + l15][grp * 8]);
                #pragma unroll
                for (int p = 0; p < 4; ++p) {
                    if (p < nch) {
                        s8v a = *reinterpret_cast<const s8v*>(&As[cur][p * 64 + w * 16 + l15][grp * 8]);
                        #pragma unroll
                        for (int f = 0; f < 8; ++f)
                            acc[p][f] = __builtin_amdgcn_mfma_f32_16x16x32_bf16(a, bf[f], acc[p][f], 0, 0, 0);
                    }
                }
            }
            // pack + write tile t+1 into the other buffer (vmcnt wait lands here, after MFMA)
            if (t + 1 < NTG) {
                int nxt = cur ^ 1;
                unsigned int bw[8];
                #pragma unroll
                for (int j = 0; j < 8; ++j) bw[j] = pack2(pb[2 * j], pb[2 * j + 1]);
                *reinterpret_cast<int4*>(&Bt[nxt][colB][khalf * 16])     = make_int4(bw[0], bw[1], bw[2], bw[3]);
                *reinterpret_cast<int4*>(&Bt[nxt][colB][khalf * 16 + 8]) = make_int4(bw[4], bw[5], bw[6], bw[7]);
                #pragma unroll
                for (int p = 0; p < 4; ++p) {
                    if (p < nch) {
                        int4 ao;
                        ao.x = (int)pack2(pa0[p].x, pa0[p].y);
                        ao.y = (int)pack2(pa0[p].z, pa0[p].w);
                        ao.z = (int)pack2(pa1[p].x, pa1[p].y);
                        ao.w = (int)pack2(pa1[p].z, pa1[p].w);
                        *reinterpret_cast<int4*>(&As[nxt][p * 64 + arow][aq * 8]) = ao;
                    }
                }
            }
            __syncthreads();
        }

        // epilogue for this super-pass
        #pragma unroll
        for (int p = 0; p < 4; ++p) {
            if (p < nch) {
                #pragma unroll
                for (int f = 0; f < 4; ++f) {
                    #pragma unroll
                    for (int r = 0; r < 4; ++r) {
                        int rg = s0 + p * 64 + w * 16 + grp * 4 + r;
                        if (rg < rows) {
                            float g = acc[p][f][r];
                            float u = acc[p][f + 4][r];
                            float hv = (g / (1.f + expf(-g))) * u;
                            hws[(size_t)(off_e + rg) * I_DIM + (c0 + f * 16 + l15)] = f2bf(hv);
                        }
                    }
                }
            }
        }
    }
}

// ---------------- GEMM B (r7-861 body + expert->XCD swizzle) --------
// flat grid 16*64; bid = g*(16*8) + s*8 + (e&7)
__global__ __launch_bounds__(256, 2) void gemm_down_kernel(const unsigned short* __restrict__ hws,
                                                           const float* __restrict__ dwn,
                                                           const int* __restrict__ slot,
                                                           const int* __restrict__ cnt,
                                                           const int* __restrict__ offs,
                                                           const float* __restrict__ topw,
                                                           float* __restrict__ out,
                                                           unsigned short* __restrict__ ye,
                                                           int use_ye) {
    int bid = blockIdx.x;
    int xl = bid & 7;
    int tq = bid >> 3;
    int s  = tq % 16;
    int e  = (tq / 16) * 8 + xl;
    int rows = min(cnt[e], CAP);
    int c0 = s * 128;
    int off_e = offs[e];

    __shared__ unsigned short As[2][RCHG][40];
    __shared__ unsigned short Bt[2][128][40];

    int tid = threadIdx.x;
    int w = tid >> 6, lane = tid & 63, grp = lane >> 4, l15 = lane & 15;

    int colB = tid & 127, khalf = tid >> 7;
    const float* bbase = dwn + ((size_t)e * I_DIM + khalf * 16) * H_DIM + c0 + colB;

    int arow = tid >> 2, aq = tid & 3;

    for (int s0 = 0; s0 < rows; s0 += RCHG) {
        int nch = min(4, (rows - s0 + 63) >> 6);
        const unsigned short* ab[4];
        #pragma unroll
        for (int p = 0; p < 4; ++p) {
            int rg = s0 + p * 64 + arow;
            ab[p] = hws + (size_t)(off_e + min(rg, rows - 1)) * I_DIM + aq * 8;
        }

        f32x4 acc[4][8];
        #pragma unroll
        for (int p = 0; p < 4; ++p)
            #pragma unroll
            for (int f = 0; f < 8; ++f) acc[p][f] = (f32x4){0.f, 0.f, 0.f, 0.f};

        float pb[16];
        int4 pa[4];

        #pragma unroll
        for (int j = 0; j < 16; ++j) pb[j] = bbase[(size_t)j * H_DIM];
        #pragma unroll
        for (int p = 0; p < 4; ++p)
            if (p < nch) pa[p] = *reinterpret_cast<const int4*>(ab[p]);
        {
            unsigned int bw[8];
            #pragma unroll
            for (int j = 0; j < 8; ++j) bw[j] = pack2(pb[2 * j], pb[2 * j + 1]);
            *reinterpret_cast<int4*>(&Bt[0][colB][khalf * 16])     = make_int4(bw[0], bw[1], bw[2], bw[3]);
            *reinterpret_cast<int4*>(&Bt[0][colB][khalf * 16 + 8]) = make_int4(bw[4], bw[5], bw[6], bw[7]);
            #pragma unroll
            for (int p = 0; p < 4; ++p)
                if (p < nch) *reinterpret_cast<int4*>(&As[0][p * 64 + arow][aq * 8]) = pa[p];
        }
        __syncthreads();

        for (int t = 0; t < NTD; ++t) {
            int cur = t & 1;
            int kn = (t + 1) * 32;
            if (t + 1 < NTD) {
                #pragma unroll
                for (int j = 0; j < 16; ++j) pb[j] = bbase[(size_t)(kn + j) * H_DIM];
                #pragma unroll
                for (int p = 0; p < 4; ++p)
                    if (p < nch) pa[p] = *reinterpret_cast<const int4*>(ab[p] + kn);
            }
            {
                s8v bf[8];
                #pragma unroll
                for (int f = 0; f < 8; ++f)
                    bf[f] = *reinterpret_cast<const s8v*>(&Bt[cur][f * 16 + l15][grp * 8]);
                #pragma unroll
                for (int p = 0; p < 4; ++p) {
                    if (p < nch) {
                        s8v a = *reinterpret_cast<const s8v*>(&As[cur][p * 64 + w * 16 + l15][grp * 8]);
                        #pragma unroll
                        for (int f = 0; f < 8; ++f)
                            acc[p][f] = __builtin_amdgcn_mfma_f32_16x16x32_bf16(a, bf[f], acc[p][f], 0, 0, 0);
                    }
                }
            }
            if (t + 1 < NTD) {
                int nxt = cur ^ 1;
                unsigned int bw[8];
                #pragma unroll
                for (int j = 0; j < 8; ++j) bw[j] = pack2(pb[2 * j], pb[2 * j + 1]);
                *reinterpret_cast<int4*>(&Bt[nxt][colB][khalf * 16])     = make_int4(bw[0], bw[1], bw[2], bw[3]);
                *reinterpret_cast<int4*>(&Bt[nxt][colB][khalf * 16 + 8]) = make_int4(bw[4], bw[5], bw[6], bw[7]);
                #pragma unroll
                for (int p = 0; p < 4; ++p)
                    if (p < nch) *reinterpret_cast<int4*>(&As[nxt][p * 64 + arow][aq * 8]) = pa[p];
            }
            __syncthreads();
        }

        if (use_ye) {
            #pragma unroll
            for (int p = 0; p < 4; ++p) {
                if (p < nch) {
                    #pragma unroll
                    for (int r = 0; r < 4; ++r) {
                        int rg = s0 + p * 64 + w * 16 + grp * 4 + r;
                        if (rg < rows) {
                            unsigned short* yrow = ye + (size_t)(off_e + rg) * H_DIM + c0 + l15;
                            #pragma unroll
                            for (int f = 0; f < 8; ++f)
                                yrow[f * 16] = f2bf(acc[p][f][r]);
                        }
                    }
                }
            }
        } else {
            #pragma unroll
            for (int p = 0; p < 4; ++p) {
                if (p < nch) {
                    #pragma unroll
                    for (int r = 0; r < 4; ++r) {
                        int rg = s0 + p * 64 + w * 16 + grp * 4 + r;
                        if (rg < rows) {
                            int ent2 = slot[e * CAP + rg];
                            float wgt = topw[ent2];
                            float* obase = out + (size_t)(ent2 >> 3) * H_DIM + c0 + l15;
                            #pragma unroll
                            for (int f = 0; f < 8; ++f)
                                atomicAdd(obase + f * 16, wgt * acc[p][f][r]);
                        }
                    }
                }
            }
        }
    }
}

// ---------------- combine (ye path) ----------------
__global__ __launch_bounds__(256) void combine_kernel(const unsigned short* __restrict__ ye,
                                                      const int* __restrict__ topi,
                                                      const float* __restrict__ topw,
                                                      const int* __restrict__ epos,
                                                      const int* __restrict__ offs,
                                                      float* __restrict__ out) {
    int t = blockIdx.x;
    int tid = threadIdx.x;
    int base = t * TOPK;
    float acc[8];
    #pragma unroll
    for (int j = 0; j < 8; ++j) acc[j] = 0.f;
    #pragma unroll
    for (int k = 0; k < TOPK; ++k) {
        int e = topi[base + k];
        int p = epos[base + k];
        if (p < CAP) {
            int row = offs[e] + p;
            float wk = topw[base + k];
            int4 v = *reinterpret_cast<const int4*>(ye + (size_t)row * H_DIM + tid * 8);
            const unsigned short* vp = reinterpret_cast<const unsigned short*>(&v);
            #pragma unroll
            for (int j = 0; j < 8; ++j)
                acc[j] += wk * __uint_as_float(((unsigned int)vp[j]) << 16);
        }
    }
    float* orow = out + (size_t)t * H_DIM + tid * 8;
    *reinterpret_cast<float4*>(orow)     = make_float4(acc[0], acc[1], acc[2], acc[3]);
    *reinterpret_cast<float4*>(orow + 4) = make_float4(acc[4], acc[5], acc[6], acc[7]);
}

extern "C" void kernel_launch(void* const* d_in, const int* in_sizes, int n_in,
                              void* d_out, int out_size, void* d_ws, size_t ws_size,
                              hipStream_t stream) {
    const float* x   = (const float*)d_in[0];
    const float* wr  = (const float*)d_in[1];
    const float* gup = (const float*)d_in[2];
    const float* dwn = (const float*)d_in[3];
    float* out = (float*)d_out;
    char* ws = (char*)d_ws;

    int*            topi = (int*)(ws + 0);         //  64 KB
    float*          topw = (float*)(ws + 65536);   //  64 KB
    int*            cnt  = (int*)(ws + 131072);    // 256 B
    int*            offs = (int*)(ws + 131328);    // 256 B
    int*            epos = (int*)(ws + 131584);    //  64 KB
    int*            slot = (int*)(ws + 197120);    // 256 KB
    unsigned short* hws  = (unsigned short*)(ws + 459264);   // 24 MB
    unsigned short* ye   = (unsigned short*)(ws + 33554432); // 64 MB (ye path only)

    int use_ye = (ws_size >= (size_t)100663296) ? 1 : 0;

    init_cnt_kernel<<<1, 64, 0, stream>>>(cnt);
    if (!use_ye) {
        int n4 = out_size / 4;
        zero_out_kernel<<<(n4 + 255) / 256, 256, 0, stream>>>(out, n4);
    }
    router_kernel<<<T_TOKENS / 4, 256, 0, stream>>>(x, wr, topi, topw);
    dispatch_kernel<<<TK / 256, 256, 0, stream>>>(topi, cnt, slot, epos);
    offs_kernel<<<1, 64, 0, stream>>>(cnt, offs);
    gemm_gu_kernel<<<12 * 64, 256, 0, stream>>>(x, gup, slot, cnt, offs, hws);
    gemm_down_kernel<<<16 * 64, 256, 0, stream>>>(hws, dwn, slot, cnt, offs, topw, out, ye, use_ye);
    if (use_ye)
        combine_kernel<<<T_TOKENS, 256, 0, stream>>>(ye, topi, topw, epos, offs, out);
}